// Round 6
// baseline (291.781 us; speedup 1.0000x reference)
//
#include <hip/hip_runtime.h>

// AggregateSet fused kernel, MI355X (gfx950).
// Shapes: B=1024, M_ELEM=128, D_IN=64, D_HID=256, H=8, D_K=D_V=64.
// R5: A-operand register-resident. R4 was LDS-pipe-bound (384KB/wave of
// ds_read_b128 A-frags; MfmaUtil 38% ~= predicted 30% from LDS saturation).
// Now: wave owns 32 rows; af[2][8] = 64 VGPRs hold its whole A (16KB),
// loaded ONCE via a wave-PRIVATE 4KB swizzled staging buffer (no barriers).
// 8 waves = 2 halves x 4 rgroups; wave handles its half's 4 heads in 2
// head-pair passes; softmax reduces across the 4 rgroups (2 barriers/pass,
// 5 total). LDS 41KB -> 2 blocks/CU. GEMM1 computed twice (once per half,
// +4% MFMA). prep_weights: LDS tile-transpose, coalesced in+out.
// K-permutation identical for A and B frags (cancels inside MFMA).

typedef __attribute__((ext_vector_type(8))) short bf16x8;
typedef __attribute__((ext_vector_type(4))) float f32x4;

#define XROW 8320
#define MASK_OFF 8192

static __device__ __forceinline__ short f2bf(float f) {
  union { float f; unsigned u; } v; v.f = f;
  unsigned r = v.u + 0x7FFFu + ((v.u >> 16) & 1u);  // RNE
  return (short)(r >> 16);
}
static __device__ __forceinline__ f32x4 splat4(float v) {
  f32x4 r = {v, v, v, v};
  return r;
}

// ---------------------------------------------------------------------------
// Weight prep: fp32 row-major W[k][n] -> bf16 in MFMA FRAGMENT ORDER.
// Wsub (K=64,N=256):  idx = t*1024 + ks1*512 + lg*128 + l15*8 + j
//                     n = 16t+l15, k = 32ks1+8lg+j          (16384 shorts)
// Wq/Wk/Wv (K=256,N=512): idx = t*4096 + ks*512 + lg*128 + l15*8 + j
//                     n = 16t+l15, k = 32ks+8lg+j           (131072 each)
// Coalesced read (16-col tiles through padded LDS) + coalesced write.
__global__ __launch_bounds__(256) void prep_weights(
    const float* __restrict__ Ws, const float* __restrict__ Wq,
    const float* __restrict__ Wk, const float* __restrict__ Wv,
    short* __restrict__ wt)
{
  __shared__ float lt[256 * 17];
  const int bid = blockIdx.x, tid = threadIdx.x;
  if (bid < 96) {
    const int m = bid >> 5, t = bid & 31;
    const float* W = (m == 0) ? Wq : (m == 1) ? Wk : Wv;
    #pragma unroll
    for (int rep = 0; rep < 16; ++rep) {
      int k = rep * 16 + (tid >> 4), n = tid & 15;
      lt[k * 17 + n] = W[k * 512 + 16 * t + n];
    }
    __syncthreads();
    bf16x8 o0, o1;
    const int ol = tid * 16;
    #pragma unroll
    for (int s = 0; s < 16; ++s) {
      int o = ol + s;
      int ks = (o >> 9) & 7, g2 = (o >> 7) & 3, n16 = (o >> 3) & 15, j = o & 7;
      int k = 32 * ks + 8 * g2 + j;
      short v = f2bf(lt[k * 17 + n16]);
      if (s < 8) o0[s] = v; else o1[s - 8] = v;
    }
    short* dst = wt + 16384 + m * 131072 + t * 4096 + ol;
    *(bf16x8*)dst = o0;
    *(bf16x8*)(dst + 8) = o1;
  } else {
    const int t = bid - 96;
    #pragma unroll
    for (int rep = 0; rep < 4; ++rep) {
      int k = rep * 16 + (tid >> 4), n = tid & 15;
      lt[k * 17 + n] = Ws[k * 256 + 16 * t + n];
    }
    __syncthreads();
    short4 o;
    const int ol = tid * 4;
    #pragma unroll
    for (int s = 0; s < 4; ++s) {
      int o_ = ol + s;
      int ks1 = (o_ >> 9) & 1, g2 = (o_ >> 7) & 3, n16 = (o_ >> 3) & 15, j = o_ & 7;
      int k = 32 * ks1 + 8 * g2 + j;
      short v = f2bf(lt[k * 17 + n16]);
      if (s == 0) o.x = v; else if (s == 1) o.y = v; else if (s == 2) o.z = v; else o.w = v;
    }
    *(short4*)(wt + t * 1024 + ol) = o;
  }
}

// ---------------------------------------------------------------------------
static __device__ __forceinline__ void qk_head(
    const bf16x8 (&af0)[8], const bf16x8 (&af1)[8],
    const short* __restrict__ baseq, const short* __restrict__ basek,
    float biq, float bik, float (&pl)[8])
{
  f32x4 aq0 = splat4(biq), aq1 = splat4(biq);
  f32x4 ak0 = splat4(bik), ak1 = splat4(bik);
  #pragma unroll
  for (int ks = 0; ks < 8; ++ks) {
    bf16x8 bqf = *(const bf16x8*)(baseq + ks * 512);
    bf16x8 bkf = *(const bf16x8*)(basek + ks * 512);
    aq0 = __builtin_amdgcn_mfma_f32_16x16x32_bf16(af0[ks], bqf, aq0, 0, 0, 0);
    aq1 = __builtin_amdgcn_mfma_f32_16x16x32_bf16(af1[ks], bqf, aq1, 0, 0, 0);
    ak0 = __builtin_amdgcn_mfma_f32_16x16x32_bf16(af0[ks], bkf, ak0, 0, 0, 0);
    ak1 = __builtin_amdgcn_mfma_f32_16x16x32_bf16(af1[ks], bkf, ak1, 0, 0, 0);
  }
  #pragma unroll
  for (int r = 0; r < 4; ++r) {
    pl[r]     += aq0[r] * ak0[r];
    pl[4 + r] += aq1[r] * ak1[r];
  }
}

static __device__ __forceinline__ float v_head_nt(
    const bf16x8 (&af0)[8], const bf16x8 (&af1)[8],
    const short* __restrict__ basev, float biv, const float (&pl)[8])
{
  f32x4 av0 = splat4(biv), av1 = splat4(biv);
  #pragma unroll
  for (int ks = 0; ks < 8; ++ks) {
    bf16x8 bvf = *(const bf16x8*)(basev + ks * 512);
    av0 = __builtin_amdgcn_mfma_f32_16x16x32_bf16(af0[ks], bvf, av0, 0, 0, 0);
    av1 = __builtin_amdgcn_mfma_f32_16x16x32_bf16(af1[ks], bvf, av1, 0, 0, 0);
  }
  float t = 0.f;
  #pragma unroll
  for (int r = 0; r < 4; ++r)
    t += pl[r] * av0[r] + pl[4 + r] * av1[r];
  return t;
}

__global__ __launch_bounds__(512, 2) void fused_kernel(
    const float* __restrict__ x,
    const float* __restrict__ bsub, const float* __restrict__ bq,
    const float* __restrict__ bk,   const float* __restrict__ bv,
    const short* __restrict__ wt,   float* __restrict__ out)
{
  // smem: [0,32768) per-wave staging (8 x 2048 shorts);
  //       [32768,40960) plbuf [8h][4nt][4rg][16d] floats;
  //       [40960,41216) red: [h*4+rg] max (32 f) then +32 esum (32 f).
  __shared__ char smem[41216];
  short* sb    = (short*)smem;
  float* plbuf = (float*)(smem + 32768);
  float* red   = (float*)(smem + 40960);

  const int b   = blockIdx.x;
  const int tid = threadIdx.x;
  const int w   = tid >> 6;
  const int l   = tid & 63;
  const int l15 = l & 15;
  const int lg  = l >> 4;
  const int rg  = w & 3;          // row-group: rows 32*rg .. +31
  const int hb  = (w >> 2) * 4;   // this half's heads: hb..hb+3
  const int R   = 32 * rg;

  const float* xb  = x + (size_t)b * XROW;
  const short* wts = wt;
  const short* wtq = wt + 16384;
  const short* wtk = wtq + 131072;
  const short* wtv = wtk + 131072;
  short* sbw = sb + w * 2048;     // wave-private 4KB staging

  // ---- GEMM1 A-frags from x (rows R..R+31, K=64) ----
  bf16x8 a1[2][2];
  #pragma unroll
  for (int m = 0; m < 2; ++m)
    #pragma unroll
    for (int ks1 = 0; ks1 < 2; ++ks1) {
      int e = R + 16 * m + l15;
      const float* p = xb + e * 64 + 32 * ks1 + 8 * lg;
      float4 f0 = *(const float4*)p;
      float4 f1 = *(const float4*)(p + 4);
      bf16x8 t;
      t[0] = f2bf(f0.x); t[1] = f2bf(f0.y); t[2] = f2bf(f0.z); t[3] = f2bf(f0.w);
      t[4] = f2bf(f1.x); t[5] = f2bf(f1.y); t[6] = f2bf(f1.z); t[7] = f2bf(f1.w);
      a1[m][ks1] = t;
    }

  // ---- GEMM1 (activ rows R..R+31) -> wave-private staging -> af regs ----
  // staging layout (per 64-col quarter): value(row er, col c) at
  // sbw[er*64 + ((c>>3) ^ (er&7))*8 + (c&7)]  (16B-granule XOR swizzle)
  bf16x8 af0[8], af1[8];   // [ks]: A-frag rows (R+l15) / (R+16+l15), k=32ks+8lg+j
  #pragma unroll
  for (int Q = 0; Q < 4; ++Q) {
    #pragma unroll
    for (int t2 = 0; t2 < 4; ++t2) {
      const int t = 4 * Q + t2;
      f32x4 acc0 = splat4(bsub[16 * t + l15]);
      f32x4 acc1 = acc0;
      #pragma unroll
      for (int ks1 = 0; ks1 < 2; ++ks1) {
        bf16x8 bfw = *(const bf16x8*)(wts + t * 1024 + ks1 * 512 + lg * 128 + l15 * 8);
        acc0 = __builtin_amdgcn_mfma_f32_16x16x32_bf16(a1[0][ks1], bfw, acc0, 0, 0, 0);
        acc1 = __builtin_amdgcn_mfma_f32_16x16x32_bf16(a1[1][ks1], bfw, acc1, 0, 0, 0);
      }
      #pragma unroll
      for (int r = 0; r < 4; ++r) {
        int c = 16 * t2 + l15;
        int e0 = 4 * lg + r;          // m=0 local row
        int e1 = 16 + 4 * lg + r;     // m=1 local row
        sbw[e0 * 64 + (((c >> 3) ^ (e0 & 7)) << 3) + (c & 7)] = f2bf(acc0[r]);
        sbw[e1 * 64 + (((c >> 3) ^ (e1 & 7)) << 3) + (c & 7)] = f2bf(acc1[r]);
      }
    }
    // read back this quarter's A-frags (wave-local; compiler inserts lgkmcnt)
    #pragma unroll
    for (int kk = 0; kk < 2; ++kk) {
      int g = 4 * kk + lg;
      af0[2 * Q + kk] = *(const bf16x8*)(sbw + l15 * 64 + ((g ^ (l15 & 7)) << 3));
      af1[2 * Q + kk] = *(const bf16x8*)(sbw + (16 + l15) * 64 + ((g ^ (l15 & 7)) << 3));
    }
  }

  // ---- per head-pair: qk -> cross-rgroup softmax -> v -> plbuf ----
  #pragma unroll 1
  for (int hp = 0; hp < 2; ++hp) {
    const int h0 = hb + 2 * hp, h1 = h0 + 1;
    float pl0[8], pl1[8];
    #pragma unroll
    for (int i = 0; i < 8; ++i) { pl0[i] = 0.f; pl1[i] = 0.f; }

    #pragma unroll 1
    for (int nt = 0; nt < 4; ++nt) {
      qk_head(af0, af1,
              wtq + (4 * h0 + nt) * 4096 + lg * 128 + l15 * 8,
              wtk + (4 * h0 + nt) * 4096 + lg * 128 + l15 * 8,
              bq[h0 * 64 + 16 * nt + l15], bk[h0 * 64 + 16 * nt + l15], pl0);
      qk_head(af0, af1,
              wtq + (4 * h1 + nt) * 4096 + lg * 128 + l15 * 8,
              wtk + (4 * h1 + nt) * 4096 + lg * 128 + l15 * 8,
              bq[h1 * 64 + 16 * nt + l15], bk[h1 * 64 + 16 * nt + l15], pl1);
    }
    // d-reduce over 16 lanes; scale 1/sqrt(64)
    #pragma unroll
    for (int i = 0; i < 8; ++i) {
      float s0 = pl0[i], s1 = pl1[i];
      s0 += __shfl_xor(s0, 1); s1 += __shfl_xor(s1, 1);
      s0 += __shfl_xor(s0, 2); s1 += __shfl_xor(s1, 2);
      s0 += __shfl_xor(s0, 4); s1 += __shfl_xor(s1, 4);
      s0 += __shfl_xor(s0, 8); s1 += __shfl_xor(s1, 8);
      pl0[i] = s0 * 0.125f;
      pl1[i] = s1 * 0.125f;
    }

    // masks for own rows (L1-hot re-read; keeps VGPR pressure down)
    float mreg[8];
    #pragma unroll
    for (int m = 0; m < 2; ++m)
      #pragma unroll
      for (int r = 0; r < 4; ++r)
        mreg[m * 4 + r] = xb[MASK_OFF + R + 16 * m + 4 * lg + r];

    // local masked max (relu floor 0), reduce over lg then rgroups
    float z0 = 0.f, z1 = 0.f;
    #pragma unroll
    for (int i = 0; i < 8; ++i) {
      z0 = fmaxf(z0, (mreg[i] > 0.f) ? pl0[i] : 0.f);
      z1 = fmaxf(z1, (mreg[i] > 0.f) ? pl1[i] : 0.f);
    }
    z0 = fmaxf(z0, __shfl_xor(z0, 16)); z0 = fmaxf(z0, __shfl_xor(z0, 32));
    z1 = fmaxf(z1, __shfl_xor(z1, 16)); z1 = fmaxf(z1, __shfl_xor(z1, 32));
    if (l == 0) { red[h0 * 4 + rg] = z0; red[h1 * 4 + rg] = z1; }
    __syncthreads();
    float zg0 = fmaxf(fmaxf(red[h0 * 4], red[h0 * 4 + 1]),
                      fmaxf(red[h0 * 4 + 2], red[h0 * 4 + 3]));
    float zg1 = fmaxf(fmaxf(red[h1 * 4], red[h1 * 4 + 1]),
                      fmaxf(red[h1 * 4 + 2], red[h1 * 4 + 3]));

    float e0 = 0.f, e1 = 0.f;
    #pragma unroll
    for (int i = 0; i < 8; ++i) {
      float v0 = (mreg[i] > 0.f) ? __expf(pl0[i] - zg0) : 0.f;
      float v1 = (mreg[i] > 0.f) ? __expf(pl1[i] - zg1) : 0.f;
      pl0[i] = v0; e0 += v0;
      pl1[i] = v1; e1 += v1;
    }
    e0 += __shfl_xor(e0, 16); e0 += __shfl_xor(e0, 32);
    e1 += __shfl_xor(e1, 16); e1 += __shfl_xor(e1, 32);
    if (l == 0) { red[32 + h0 * 4 + rg] = e0; red[32 + h1 * 4 + rg] = e1; }
    __syncthreads();
    float inv0 = 1.f / (red[32 + h0 * 4] + red[32 + h0 * 4 + 1] +
                        red[32 + h0 * 4 + 2] + red[32 + h0 * 4 + 3] + 1.f);
    float inv1 = 1.f / (red[32 + h1 * 4] + red[32 + h1 * 4 + 1] +
                        red[32 + h1 * 4 + 2] + red[32 + h1 * 4 + 3] + 1.f);
    #pragma unroll
    for (int i = 0; i < 8; ++i) { pl0[i] *= inv0; pl1[i] *= inv1; }

    // v projection + pooled partials (this wave's 32 rows)
    #pragma unroll 1
    for (int nt = 0; nt < 4; ++nt) {
      float t0 = v_head_nt(af0, af1, wtv + (4 * h0 + nt) * 4096 + lg * 128 + l15 * 8,
                           bv[h0 * 64 + 16 * nt + l15], pl0);
      float t1 = v_head_nt(af0, af1, wtv + (4 * h1 + nt) * 4096 + lg * 128 + l15 * 8,
                           bv[h1 * 64 + 16 * nt + l15], pl1);
      t0 += __shfl_xor(t0, 16); t0 += __shfl_xor(t0, 32);
      t1 += __shfl_xor(t1, 16); t1 += __shfl_xor(t1, 32);
      if (lg == 0) {
        plbuf[((h0 * 4 + nt) * 4 + rg) * 16 + l15] = t0;
        plbuf[((h1 * 4 + nt) * 4 + rg) * 16 + l15] = t1;
      }
    }
  }
  __syncthreads();

  // ---- final: sum the 4 rgroup partials; one output element per thread ----
  {
    const int h = tid >> 6, nt = (tid >> 4) & 3, d = tid & 15;
    const float* pp = plbuf + (h * 4 + nt) * 64 + d;
    out[b * 513 + h * 64 + nt * 16 + d] = pp[0] + pp[16] + pp[32] + pp[48];
  }
  // elem_frac (exact: mask is 0/1)
  if (tid < 64) {
    float s = xb[MASK_OFF + tid] + xb[MASK_OFF + tid + 64];
    #pragma unroll
    for (int off = 32; off > 0; off >>= 1) s += __shfl_xor(s, off);
    if (tid == 0) out[b * 513 + 512] = s * (1.f / 128.f);
  }
}

extern "C" void kernel_launch(void* const* d_in, const int* in_sizes, int n_in,
                              void* d_out, int out_size, void* d_ws, size_t ws_size,
                              hipStream_t stream) {
  (void)in_sizes; (void)n_in; (void)out_size; (void)ws_size;
  const float* x    = (const float*)d_in[0];
  const float* Wsub = (const float*)d_in[1];
  const float* bsub = (const float*)d_in[2];
  const float* Wq   = (const float*)d_in[3];
  const float* bq   = (const float*)d_in[4];
  const float* Wk   = (const float*)d_in[5];
  const float* bk   = (const float*)d_in[6];
  const float* Wv   = (const float*)d_in[7];
  const float* bv   = (const float*)d_in[8];
  float* out = (float*)d_out;
  short* wt  = (short*)d_ws;   // 800 KB used

  prep_weights<<<112, 256, 0, stream>>>(Wsub, Wq, Wk, Wv, wt);
  fused_kernel<<<1024, 512, 0, stream>>>(x, bsub, bq, bk, bv, wt, out);
}